// Round 5
// baseline (361.277 us; speedup 1.0000x reference)
//
#include <hip/hip_runtime.h>
#include <math.h>

#define D 128
#define BN_EPS 1e-3f
#define L2_EPS 1e-12f
#define AGG_S 136  // ushort stride for 16x128 bf16 LDS tile (+8 pad => bank spread)
#define OUT_S 392  // float stride for 16x384 f32 out tile (+8 pad, 16B aligned)

typedef unsigned int uint;
typedef unsigned short ushort;
typedef __attribute__((ext_vector_type(8))) short bf16x8;  // 8 bf16 in 4 VGPRs
typedef __attribute__((ext_vector_type(4))) float f32x4;

__device__ __forceinline__ ushort f2bf(float f) {
  uint u = __float_as_uint(f);
  uint r = (u + 0x7fffu + ((u >> 16) & 1u)) >> 16;
  return (ushort)r;
}
__device__ __forceinline__ float bflo(uint u) { return __uint_as_float(u << 16); }
__device__ __forceinline__ float bfhi(uint u) { return __uint_as_float(u & 0xffff0000u); }
__device__ __forceinline__ float bf2f(ushort h) { return __uint_as_float(((uint)h) << 16); }

// ---------------------------------------------------------------------------
// Device helpers for the fused prep kernel
// ---------------------------------------------------------------------------
__device__ __forceinline__ void pack_bfrag_block(
    const float* __restrict__ W, const float* __restrict__ gamma,
    const float* __restrict__ var, ushort* __restrict__ Bf, int blk, int tid) {
  int t = blk * 256 + tid;  // 0..2047
  int f = t >> 6, lane = t & 63;
  int kc = f >> 3, nt = f & 7, q = lane >> 4, m = lane & 15;
  ushort tmp[8];
#pragma unroll
  for (int j = 0; j < 8; ++j) {
    int k = kc * 32 + q * 8 + j;
    float s = gamma[k] * rsqrtf(var[k] + BN_EPS);
    tmp[j] = f2bf(s * W[k * D + nt * 16 + m]);
  }
  uint4 o;
  o.x = (uint)tmp[0] | ((uint)tmp[1] << 16);
  o.y = (uint)tmp[2] | ((uint)tmp[3] << 16);
  o.z = (uint)tmp[4] | ((uint)tmp[5] << 16);
  o.w = (uint)tmp[6] | ((uint)tmp[7] << 16);
  reinterpret_cast<uint4*>(Bf)[t] = o;
}

__device__ __forceinline__ void bn_bias_block(
    const float* __restrict__ W, const float* __restrict__ gamma,
    const float* __restrict__ beta, const float* __restrict__ mean,
    const float* __restrict__ var, float* __restrict__ outb, int j) {
  float acc = 0.f;
  for (int k = 0; k < D; ++k) {
    float s = gamma[k] * rsqrtf(var[k] + BN_EPS);
    float sh = beta[k] - mean[k] * s;
    acc += sh * W[k * D + j];
  }
  outb[j] = acc;
}

// ---------------------------------------------------------------------------
// Fused prep: [0,nbConv) f32->bf16 | [+nbRp) row_ptr + degree histogram |
// +8 Bf1 | +8 Bf2 | +1 bnb | +1 shd | rest: packed edge arrays
// ew1=(col,adj), ew2=(col, adj/(relc[rel]+1)), pad (0,0) at index e.
// hist[256] must be zeroed before launch (hipMemsetAsync).
// ---------------------------------------------------------------------------
__global__ __launch_bounds__(256) void prep_kernel(
    const float* __restrict__ x, ushort* __restrict__ xbf, int n4,
    const int* __restrict__ rows, int* __restrict__ row_ptr,
    uint* __restrict__ hist, int n, int e,
    const float* __restrict__ W1, const float* __restrict__ g1,
    const float* __restrict__ v1, ushort* __restrict__ Bf1,
    const float* __restrict__ Wd, const float* __restrict__ g2,
    const float* __restrict__ v2, ushort* __restrict__ Bf2,
    const float* __restrict__ beta1, const float* __restrict__ mean1,
    float* __restrict__ bnb,
    const float* __restrict__ beta2, const float* __restrict__ mean2,
    float* __restrict__ shd,
    const int* __restrict__ cols, const float* __restrict__ adj,
    const int* __restrict__ rel, const float* __restrict__ relc,
    uint2* __restrict__ ew1, uint2* __restrict__ ew2,
    int nbConv, int nbRp) {
  const int b = blockIdx.x, tid = threadIdx.x;
  if (b < nbConv) {
    int i = b * 256 + tid;
    if (i < n4) {
      float4 v = reinterpret_cast<const float4*>(x)[i];
      ushort4 o;
      o.x = f2bf(v.x); o.y = f2bf(v.y); o.z = f2bf(v.z); o.w = f2bf(v.w);
      reinterpret_cast<ushort4*>(xbf)[i] = o;
    }
    return;
  }
  int bb = b - nbConv;
  if (bb < nbRp) {
    int i = bb * 256 + tid;
    if (i <= n) {
      int lo = 0, hi = e;
      while (lo < hi) {
        int mid = (lo + hi) >> 1;
        if (rows[mid] < i) lo = mid + 1; else hi = mid;
      }
      row_ptr[i] = lo;
      if (i < n) {  // degree of row i via second search (start from lo)
        int lo2 = lo, hi2 = e;
        while (lo2 < hi2) {
          int mid = (lo2 + hi2) >> 1;
          if (rows[mid] < i + 1) lo2 = mid + 1; else hi2 = mid;
        }
        atomicAdd(&hist[min(lo2 - lo, 255)], 1u);
      }
    }
    return;
  }
  bb -= nbRp;
  if (bb < 8) { pack_bfrag_block(W1, g1, v1, Bf1, bb, tid); return; }
  if (bb < 16) { pack_bfrag_block(Wd, g2, v2, Bf2, bb - 8, tid); return; }
  if (bb == 16) { if (tid < D) bn_bias_block(W1, g1, beta1, mean1, v1, bnb, tid); return; }
  if (bb == 17) { if (tid < D) bn_bias_block(Wd, g2, beta2, mean2, v2, shd, tid); return; }
  int i = (bb - 18) * 256 + tid;
  if (i < e) {
    uint c = (uint)cols[i];
    float a = adj[i];
    ew1[i] = make_uint2(c, __float_as_uint(a));
    float w2 = a / (relc[rel[i]] + 1.0f);
    ew2[i] = make_uint2(c, __float_as_uint(w2));
  } else if (i == e) {
    ew1[i] = make_uint2(0u, 0u);
    ew2[i] = make_uint2(0u, 0u);
  }
}

// ---------------------------------------------------------------------------
// binoff[d] = #rows with degree > d  (descending-degree counting sort bases:
// heavy blocks are scheduled first -> better grid tail).
// ---------------------------------------------------------------------------
__global__ __launch_bounds__(256) void scan_kernel(
    const uint* __restrict__ hist, uint* __restrict__ binoff) {
  __shared__ uint s[256];
  const int t = threadIdx.x;
  const uint c = hist[t];
  s[t] = c;
  __syncthreads();
  for (int off = 1; off < 256; off <<= 1) {  // suffix sums: s[t]=sum_{j>=t}c[j]
    uint v = (t + off < 256) ? s[t + off] : 0u;
    __syncthreads();
    s[t] += v;
    __syncthreads();
  }
  binoff[t] = s[t] - c;
}

// ---------------------------------------------------------------------------
// Scatter rows into perm, grouped by degree. Block-local LDS histogram ->
// one global atomicAdd per non-empty bin per block (avoids ~5k serialized
// same-address global atomics on popular bins), then LDS-rank placement.
// ---------------------------------------------------------------------------
__global__ __launch_bounds__(256) void scatter_kernel(
    const int* __restrict__ row_ptr, uint* __restrict__ binoff,
    int* __restrict__ perm, int n) {
  __shared__ uint lcnt[256], lbase[256], lrk[256];
  const int t = threadIdx.x;
  lcnt[t] = 0u; lrk[t] = 0u;
  __syncthreads();
  const int i = (int)blockIdx.x * 256 + t;
  int dg = -1;
  if (i < n) {
    dg = min(row_ptr[i + 1] - row_ptr[i], 255);
    atomicAdd(&lcnt[dg], 1u);
  }
  __syncthreads();
  if (lcnt[t] > 0u) lbase[t] = atomicAdd(&binoff[t], lcnt[t]);
  __syncthreads();
  if (i < n) {
    uint rk = atomicAdd(&lrk[dg], 1u);
    perm[lbase[dg] + rk] = i;
  }
}

// ---------------------------------------------------------------------------
// SpMM phase (CSR pull): 4 rows per wave, 16 lanes per row. Edge metas for a
// 16-edge chunk loaded cooperatively (lane m -> edge base+m) and broadcast
// via group-local __shfl; gathers issue in batches of 8 per lane. With the
// degree-sorted perm, all 4 rows of a wave have ~equal len -> mx ~= len and
// masked slots nearly vanish. r is a REAL row id; valid=false forces len=0.
// ---------------------------------------------------------------------------
template <bool SELF>
__device__ __forceinline__ float spmm_rows(
    const uint4* __restrict__ S4, const int* __restrict__ row_ptr,
    const uint2* __restrict__ ew, const float* __restrict__ ck,
    int r, bool valid, int lane, float acc[8]) {
  const int m = lane & 15;
  const int g16 = lane & 48;  // base lane of my 16-lane row group
  const int e0 = row_ptr[r];
  int len = row_ptr[r + 1] - e0;
  if (!valid) len = 0;
  int mx = len;
  mx = max(mx, __shfl_xor(mx, 16));
  mx = max(mx, __shfl_xor(mx, 32));  // wave-uniform
  const int lastOff = len > 0 ? len - 1 : 0;

#pragma unroll
  for (int j = 0; j < 8; ++j) acc[j] = 0.f;
  float ws = 0.f;

  for (int base = 0; base < mx; base += 16) {
    const int mo = base + m;
    const uint2 mym = ew[e0 + (mo < len ? mo : lastOff)];
    const float myw = (mo < len) ? __uint_as_float(mym.y) : 0.f;
#pragma unroll
    for (int h = 0; h < 2; ++h) {
      if (base + h * 8 >= mx) break;  // wave-uniform
      uint4 gv[8];
      float wv[8];
#pragma unroll
      for (int u = 0; u < 8; ++u) {
        const int src = g16 + h * 8 + u;
        const uint cidx = (uint)__shfl((int)mym.x, src);
        wv[u] = __shfl(myw, src);
        gv[u] = S4[(size_t)cidx * 16 + m];
      }
#pragma unroll
      for (int u = 0; u < 8; ++u) {
        const float w = wv[u];
        ws += w;
        acc[0] = fmaf(w, bflo(gv[u].x), acc[0]);
        acc[1] = fmaf(w, bfhi(gv[u].x), acc[1]);
        acc[2] = fmaf(w, bflo(gv[u].y), acc[2]);
        acc[3] = fmaf(w, bfhi(gv[u].y), acc[3]);
        acc[4] = fmaf(w, bflo(gv[u].z), acc[4]);
        acc[5] = fmaf(w, bfhi(gv[u].z), acc[5]);
        acc[6] = fmaf(w, bflo(gv[u].w), acc[6]);
        acc[7] = fmaf(w, bfhi(gv[u].w), acc[7]);
      }
    }
  }

  if (SELF && valid) {
    uint4 us = S4[(size_t)r * 16 + m];
    float cp = ck[r] + 1.0f;
    acc[0] = fmaf(cp, bflo(us.x), acc[0]);
    acc[1] = fmaf(cp, bfhi(us.x), acc[1]);
    acc[2] = fmaf(cp, bflo(us.y), acc[2]);
    acc[3] = fmaf(cp, bfhi(us.y), acc[3]);
    acc[4] = fmaf(cp, bflo(us.z), acc[4]);
    acc[5] = fmaf(cp, bfhi(us.z), acc[5]);
    acc[6] = fmaf(cp, bflo(us.w), acc[6]);
    acc[7] = fmaf(cp, bfhi(us.w), acc[7]);
  }
  return ws;
}

__device__ __forceinline__ uint4 pack_acc(const float acc[8]) {
  uint4 o;
  o.x = (uint)f2bf(acc[0]) | ((uint)f2bf(acc[1]) << 16);
  o.y = (uint)f2bf(acc[2]) | ((uint)f2bf(acc[3]) << 16);
  o.z = (uint)f2bf(acc[4]) | ((uint)f2bf(acc[5]) << 16);
  o.w = (uint)f2bf(acc[6]) | ((uint)f2bf(acc[7]) << 16);
  return o;
}

// ---------------------------------------------------------------------------
// Fused K2: spmm1 (16 perm-selected rows/block) + GEMM1 + tanh. Per-row
// results are independent in every phase, so tile composition by degree is
// bit-identical to natural order; writes go to true row positions (256 B
// contiguous per row).
// ---------------------------------------------------------------------------
__global__ __launch_bounds__(256) void spmm_gemm1_kernel(
    const ushort* __restrict__ src, const int* __restrict__ row_ptr,
    const uint2* __restrict__ ew, const ushort* __restrict__ Bf,
    const float* __restrict__ bnb, const float* __restrict__ b1,
    const int* __restrict__ perm, ushort* __restrict__ y1, int n) {
  __shared__ ushort aggT[16 * AGG_S];
  __shared__ ushort y1T[16 * AGG_S];
  __shared__ float rsL[16];
  __shared__ int permL[16];

  const int tid = threadIdx.x;
  const int wave = tid >> 6, lane = tid & 63;
  const int g = lane >> 4, m = lane & 15;
  const int rloc = wave * 4 + g;
  const int idx = (int)blockIdx.x * 16 + rloc;
  const bool valid = idx < n;
  if (tid < 16) {
    int pi = (int)blockIdx.x * 16 + tid;
    permL[tid] = perm[pi < n ? pi : n - 1];
  }
  const int r = perm[valid ? idx : n - 1];

  // ---- phase A: spmm into registers, stage bf16 tile in LDS ----
  float acc[8];
  float ws = spmm_rows<false>(reinterpret_cast<const uint4*>(src), row_ptr,
                              ew, nullptr, r, valid, lane, acc);
  *reinterpret_cast<uint4*>(&aggT[rloc * AGG_S + m * 8]) = pack_acc(acc);
  if (m == 0) rsL[rloc] = ws;
  __syncthreads();

  // ---- phase B: 16x128 @ 128x128 MFMA; wave handles nt = {2w, 2w+1} ----
  const bf16x8* Bv = reinterpret_cast<const bf16x8*>(Bf);
  bf16x8 af[4];
#pragma unroll
  for (int kc = 0; kc < 4; ++kc)
    af[kc] = *reinterpret_cast<const bf16x8*>(&aggT[m * AGG_S + kc * 32 + g * 8]);

  f32x4 acc2[2];
  acc2[0] = (f32x4){0.f, 0.f, 0.f, 0.f};
  acc2[1] = (f32x4){0.f, 0.f, 0.f, 0.f};
  const int nt0 = wave * 2;
#pragma unroll
  for (int kc = 0; kc < 4; ++kc) {
#pragma unroll
    for (int t = 0; t < 2; ++t) {
      bf16x8 b = Bv[(kc * 8 + nt0 + t) * 64 + lane];
      acc2[t] = __builtin_amdgcn_mfma_f32_16x16x32_bf16(b, af[kc], acc2[t], 0, 0, 0);
    }
  }

  const float rs = rsL[m];
#pragma unroll
  for (int t = 0; t < 2; ++t) {
    const int c = (nt0 + t) * 16 + g * 4;
    const float4 bn = *reinterpret_cast<const float4*>(&bnb[c]);
    const float4 bb = *reinterpret_cast<const float4*>(&b1[c]);
    ushort4 ov;
    ov.x = f2bf(tanhf(acc2[t][0] + rs * bn.x + bb.x));
    ov.y = f2bf(tanhf(acc2[t][1] + rs * bn.y + bb.y));
    ov.z = f2bf(tanhf(acc2[t][2] + rs * bn.z + bb.z));
    ov.w = f2bf(tanhf(acc2[t][3] + rs * bn.w + bb.w));
    *reinterpret_cast<ushort4*>(&y1T[m * AGG_S + c]) = ov;
  }
  __syncthreads();

  // ---- copy out: each 16-thread group writes one row's 256 B ----
  const int row = tid >> 4, col = tid & 15;
  uint4 v = *reinterpret_cast<const uint4*>(&y1T[row * AGG_S + col * 8]);
  const int gidx = (int)blockIdx.x * 16 + row;
  if (gidx < n)
    reinterpret_cast<uint4*>(y1)[(size_t)permL[row] * 16 + col] = v;
}

// ---------------------------------------------------------------------------
// Fused K3: spmm2(+self) + GEMM2 + bias + tri-L2-normalize + coalesced out.
// Cross-wave row norms via LDS partials; out staged in LDS (aliased over
// aggT) and streamed out per-row as contiguous float4 runs.
// ---------------------------------------------------------------------------
__global__ __launch_bounds__(256) void spmm_gemm2_kernel(
    const ushort* __restrict__ src /*y1bf*/, const int* __restrict__ row_ptr,
    const uint2* __restrict__ ew, const ushort* __restrict__ Bf,
    const float* __restrict__ shd, const float* __restrict__ bd,
    const float* __restrict__ ck, const float* __restrict__ x,
    const int* __restrict__ perm, float* __restrict__ out, int n) {
  __shared__ __align__(16) char smemRaw[16 * OUT_S * 4];  // outT / aggT alias
  __shared__ float rsL[16];
  __shared__ float sp0[4][16], sp1[4][16], sp2[4][16];
  __shared__ int permL[16];
  ushort* aggT = reinterpret_cast<ushort*>(smemRaw);
  float* outT = reinterpret_cast<float*>(smemRaw);

  const int tid = threadIdx.x;
  const int wave = tid >> 6, lane = tid & 63;
  const int g = lane >> 4, m = lane & 15;
  const int rloc = wave * 4 + g;
  const int idx = (int)blockIdx.x * 16 + rloc;
  const bool valid = idx < n;
  if (tid < 16) {
    int pi = (int)blockIdx.x * 16 + tid;
    permL[tid] = perm[pi < n ? pi : n - 1];
  }
  const int r = perm[valid ? idx : n - 1];

  // ---- phase A: spmm with self term ----
  float acc[8];
  float ws = spmm_rows<true>(reinterpret_cast<const uint4*>(src), row_ptr,
                             ew, ck, r, valid, lane, acc);
  *reinterpret_cast<uint4*>(&aggT[rloc * AGG_S + m * 8]) = pack_acc(acc);
  if (m == 0) rsL[rloc] = ws;
  __syncthreads();

  // ---- phase B: GEMM; lane (g,m) owns row m, cols {nt0,nt0+1}*16+g*4 ----
  const bf16x8* Bv = reinterpret_cast<const bf16x8*>(Bf);
  bf16x8 af[4];
#pragma unroll
  for (int kc = 0; kc < 4; ++kc)
    af[kc] = *reinterpret_cast<const bf16x8*>(&aggT[m * AGG_S + kc * 32 + g * 8]);

  f32x4 acc2[2];
  acc2[0] = (f32x4){0.f, 0.f, 0.f, 0.f};
  acc2[1] = (f32x4){0.f, 0.f, 0.f, 0.f};
  const int nt0 = wave * 2;
#pragma unroll
  for (int kc = 0; kc < 4; ++kc) {
#pragma unroll
    for (int t = 0; t < 2; ++t) {
      bf16x8 b = Bv[(kc * 8 + nt0 + t) * 64 + lane];
      acc2[t] = __builtin_amdgcn_mfma_f32_16x16x32_bf16(b, af[kc], acc2[t], 0, 0, 0);
    }
  }

  // x / y1 col-slices: wave w covers cols w*32..w*32+31 of every tile row.
  const int rm = permL[m];
  const int c0 = wave * 32 + g * 8;
  const float4 xv0 = *reinterpret_cast<const float4*>(&x[(size_t)rm * D + c0]);
  const float4 xv1 = *reinterpret_cast<const float4*>(&x[(size_t)rm * D + c0 + 4]);
  const uint4 yv = *reinterpret_cast<const uint4*>(&src[(size_t)rm * D + c0]);
  const float ya = bflo(yv.x), yb = bfhi(yv.x), yc = bflo(yv.y), yd = bfhi(yv.y);
  const float ye = bflo(yv.z), yf = bfhi(yv.z), yg = bflo(yv.w), yh = bfhi(yv.w);

  float s0p = xv0.x * xv0.x + xv0.y * xv0.y + xv0.z * xv0.z + xv0.w * xv0.w +
              xv1.x * xv1.x + xv1.y * xv1.y + xv1.z * xv1.z + xv1.w * xv1.w;
  float s1p = ya * ya + yb * yb + yc * yc + yd * yd +
              ye * ye + yf * yf + yg * yg + yh * yh;

  const float rbias = rsL[m] + ck[rm] + 1.0f;
  float s2p = 0.f;
#pragma unroll
  for (int t = 0; t < 2; ++t) {
    const int c = (nt0 + t) * 16 + g * 4;
    const float4 sh = *reinterpret_cast<const float4*>(&shd[c]);
    const float4 bb = *reinterpret_cast<const float4*>(&bd[c]);
    acc2[t][0] += rbias * sh.x + bb.x;
    acc2[t][1] += rbias * sh.y + bb.y;
    acc2[t][2] += rbias * sh.z + bb.z;
    acc2[t][3] += rbias * sh.w + bb.w;
    s2p += acc2[t][0] * acc2[t][0] + acc2[t][1] * acc2[t][1] +
           acc2[t][2] * acc2[t][2] + acc2[t][3] * acc2[t][3];
  }

  // reduce over the 4 g-groups (same tile row m) within the wave
  s0p += __shfl_xor(s0p, 16); s0p += __shfl_xor(s0p, 32);
  s1p += __shfl_xor(s1p, 16); s1p += __shfl_xor(s1p, 32);
  s2p += __shfl_xor(s2p, 16); s2p += __shfl_xor(s2p, 32);
  if (lane < 16) { sp0[wave][lane] = s0p; sp1[wave][lane] = s1p; sp2[wave][lane] = s2p; }
  __syncthreads();  // also separates all aggT reads from outT writes (alias)

  const float s0 = sp0[0][m] + sp0[1][m] + sp0[2][m] + sp0[3][m];
  const float s1 = sp1[0][m] + sp1[1][m] + sp1[2][m] + sp1[3][m];
  const float s2 = sp2[0][m] + sp2[1][m] + sp2[2][m] + sp2[3][m];
  const float i0 = 1.0f / sqrtf(fmaxf(s0, L2_EPS));
  const float i1 = 1.0f / sqrtf(fmaxf(s1, L2_EPS));
  const float i2 = 1.0f / sqrtf(fmaxf(s2, L2_EPS));
  const float tot = s0 * i0 * i0 + s1 * i1 * i1 + s2 * i2 * i2;
  const float sc = 1.0f / sqrtf(fmaxf(tot, L2_EPS));
  const float f0 = i0 * sc, f1 = i1 * sc, f2 = i2 * sc;

  // ---- stage normalized row into outT ----
  float* orow = &outT[m * OUT_S];
  *reinterpret_cast<float4*>(&orow[c0]) =
      make_float4(xv0.x * f0, xv0.y * f0, xv0.z * f0, xv0.w * f0);
  *reinterpret_cast<float4*>(&orow[c0 + 4]) =
      make_float4(xv1.x * f0, xv1.y * f0, xv1.z * f0, xv1.w * f0);
  *reinterpret_cast<float4*>(&orow[128 + c0]) =
      make_float4(ya * f1, yb * f1, yc * f1, yd * f1);
  *reinterpret_cast<float4*>(&orow[128 + c0 + 4]) =
      make_float4(ye * f1, yf * f1, yg * f1, yh * f1);
#pragma unroll
  for (int t = 0; t < 2; ++t) {
    const int c = (nt0 + t) * 16 + g * 4;
    *reinterpret_cast<float4*>(&orow[256 + c]) =
        make_float4(acc2[t][0] * f2, acc2[t][1] * f2, acc2[t][2] * f2, acc2[t][3] * f2);
  }
  __syncthreads();

  // ---- copy out: 16 rows x 1536 B, contiguous float4 runs per row ----
#pragma unroll
  for (int it = 0; it < 6; ++it) {
    const int ii = it * 256 + tid;         // 0..1535
    const int rw = ii / 96, cc = ii % 96;
    float4 v = *reinterpret_cast<const float4*>(&outT[rw * OUT_S + cc * 4]);
    const int gidx = (int)blockIdx.x * 16 + rw;
    if (gidx < n)
      reinterpret_cast<float4*>(out)[(size_t)permL[rw] * 96 + cc] = v;
  }
}

// ---------------------------------------------------------------------------
extern "C" void kernel_launch(void* const* d_in, const int* in_sizes, int n_in,
                              void* d_out, int out_size, void* d_ws, size_t ws_size,
                              hipStream_t stream) {
  const float* x      = (const float*)d_in[0];
  const int*   rows   = (const int*)d_in[1];
  const int*   cols   = (const int*)d_in[2];
  const float* adj    = (const float*)d_in[3];
  const int*   rel    = (const int*)d_in[4];
  const float* gamma1 = (const float*)d_in[5];
  const float* beta1  = (const float*)d_in[6];
  const float* mean1  = (const float*)d_in[7];
  const float* var1   = (const float*)d_in[8];
  const float* W1     = (const float*)d_in[9];
  const float* b1     = (const float*)d_in[10];
  const float* gamma2 = (const float*)d_in[11];
  const float* beta2  = (const float*)d_in[12];
  const float* mean2  = (const float*)d_in[13];
  const float* var2   = (const float*)d_in[14];
  const float* relc   = (const float*)d_in[15];
  const float* ck     = (const float*)d_in[16];
  const float* Wd     = (const float*)d_in[17];
  const float* bd     = (const float*)d_in[18];
  float* out = (float*)d_out;

  const int n = in_sizes[0] / D;
  const int e = in_sizes[1];
  size_t nd = (size_t)n * D;

  char* p = (char*)d_ws;
  ushort* xbf   = (ushort*)p; p += nd * 2;
  ushort* y1bf  = (ushort*)p; p += nd * 2;
  ushort* Bf1   = (ushort*)p; p += 32768;
  ushort* Bf2   = (ushort*)p; p += 32768;
  float*  bnb   = (float*)p;  p += 512;
  float*  shd   = (float*)p;  p += 512;
  p = (char*)(((uintptr_t)p + 15) & ~(uintptr_t)15);
  uint2* ew1    = (uint2*)p;  p += (size_t)(e + 1) * 8;
  uint2* ew2    = (uint2*)p;  p += (size_t)(e + 1) * 8;
  int* row_ptr  = (int*)p;    p += (size_t)(n + 1) * 4;
  uint* hist    = (uint*)p;   p += 1024;
  uint* binoff  = (uint*)p;   p += 1024;
  int* perm     = (int*)p;    p += (size_t)n * 4;

  const int n4 = (int)(nd / 4);
  const int nbConv = (n4 + 255) / 256;
  const int nbRp = (n + 1 + 255) / 256;
  const int nbEw = (e + 1 + 255) / 256;
  const int nbPrep = nbConv + nbRp + 18 + nbEw;

  (void)hipMemsetAsync(hist, 0, 256 * sizeof(uint), stream);

  prep_kernel<<<nbPrep, 256, 0, stream>>>(
      x, xbf, n4, rows, row_ptr, hist, n, e,
      W1, gamma1, var1, Bf1, Wd, gamma2, var2, Bf2,
      beta1, mean1, bnb, beta2, mean2, shd,
      cols, adj, rel, relc, ew1, ew2, nbConv, nbRp);

  scan_kernel<<<1, 256, 0, stream>>>(hist, binoff);
  scatter_kernel<<<(n + 255) / 256, 256, 0, stream>>>(row_ptr, binoff, perm, n);

  const int fblocks = (n + 15) / 16;
  spmm_gemm1_kernel<<<fblocks, 256, 0, stream>>>(
      xbf, row_ptr, ew1, Bf1, bnb, b1, perm, y1bf, n);
  spmm_gemm2_kernel<<<fblocks, 256, 0, stream>>>(
      y1bf, row_ptr, ew2, Bf2, shd, bd, ck, x, perm, out, n);
}

// Round 6
// 213.150 us; speedup vs baseline: 1.6949x; 1.6949x over previous
//
#include <hip/hip_runtime.h>
#include <math.h>

#define D 128
#define BN_EPS 1e-3f
#define L2_EPS 1e-12f
#define AGG_S 136  // ushort stride for 16x128 bf16 LDS tile (+8 pad => bank spread)

typedef unsigned int uint;
typedef unsigned short ushort;
typedef __attribute__((ext_vector_type(8))) short bf16x8;  // 8 bf16 in 4 VGPRs
typedef __attribute__((ext_vector_type(4))) float f32x4;

__device__ __forceinline__ ushort f2bf(float f) {
  uint u = __float_as_uint(f);
  uint r = (u + 0x7fffu + ((u >> 16) & 1u)) >> 16;
  return (ushort)r;
}
__device__ __forceinline__ float bflo(uint u) { return __uint_as_float(u << 16); }
__device__ __forceinline__ float bfhi(uint u) { return __uint_as_float(u & 0xffff0000u); }
__device__ __forceinline__ float bf2f(ushort h) { return __uint_as_float(((uint)h) << 16); }

// ---------------------------------------------------------------------------
// Device helpers for the fused prep kernel
// ---------------------------------------------------------------------------
__device__ __forceinline__ void pack_bfrag_block(
    const float* __restrict__ W, const float* __restrict__ gamma,
    const float* __restrict__ var, ushort* __restrict__ Bf, int blk, int tid) {
  int t = blk * 256 + tid;  // 0..2047
  int f = t >> 6, lane = t & 63;
  int kc = f >> 3, nt = f & 7, q = lane >> 4, m = lane & 15;
  ushort tmp[8];
#pragma unroll
  for (int j = 0; j < 8; ++j) {
    int k = kc * 32 + q * 8 + j;
    float s = gamma[k] * rsqrtf(var[k] + BN_EPS);
    tmp[j] = f2bf(s * W[k * D + nt * 16 + m]);
  }
  uint4 o;
  o.x = (uint)tmp[0] | ((uint)tmp[1] << 16);
  o.y = (uint)tmp[2] | ((uint)tmp[3] << 16);
  o.z = (uint)tmp[4] | ((uint)tmp[5] << 16);
  o.w = (uint)tmp[6] | ((uint)tmp[7] << 16);
  reinterpret_cast<uint4*>(Bf)[t] = o;
}

__device__ __forceinline__ void bn_bias_block(
    const float* __restrict__ W, const float* __restrict__ gamma,
    const float* __restrict__ beta, const float* __restrict__ mean,
    const float* __restrict__ var, float* __restrict__ outb, int j) {
  float acc = 0.f;
  for (int k = 0; k < D; ++k) {
    float s = gamma[k] * rsqrtf(var[k] + BN_EPS);
    float sh = beta[k] - mean[k] * s;
    acc += sh * W[k * D + j];
  }
  outb[j] = acc;
}

// ---------------------------------------------------------------------------
// Fused prep: [0,nbConv) f32->bf16 | [+nbRp) row_ptr | +8 Bf1 | +8 Bf2 |
// +1 bnb | +1 shd | rest: packed edge arrays ew1=(col,adj),
// ew2=(col, adj/(relc[rel]+1)), pad (0,0) at index e.
// (Round-5 degree histogram reverted: same-address atomics made prep 157us.)
// ---------------------------------------------------------------------------
__global__ __launch_bounds__(256) void prep_kernel(
    const float* __restrict__ x, ushort* __restrict__ xbf, int n4,
    const int* __restrict__ rows, int* __restrict__ row_ptr, int n, int e,
    const float* __restrict__ W1, const float* __restrict__ g1,
    const float* __restrict__ v1, ushort* __restrict__ Bf1,
    const float* __restrict__ Wd, const float* __restrict__ g2,
    const float* __restrict__ v2, ushort* __restrict__ Bf2,
    const float* __restrict__ beta1, const float* __restrict__ mean1,
    float* __restrict__ bnb,
    const float* __restrict__ beta2, const float* __restrict__ mean2,
    float* __restrict__ shd,
    const int* __restrict__ cols, const float* __restrict__ adj,
    const int* __restrict__ rel, const float* __restrict__ relc,
    uint2* __restrict__ ew1, uint2* __restrict__ ew2,
    int nbConv, int nbRp) {
  const int b = blockIdx.x, tid = threadIdx.x;
  if (b < nbConv) {
    int i = b * 256 + tid;
    if (i < n4) {
      float4 v = reinterpret_cast<const float4*>(x)[i];
      ushort4 o;
      o.x = f2bf(v.x); o.y = f2bf(v.y); o.z = f2bf(v.z); o.w = f2bf(v.w);
      reinterpret_cast<ushort4*>(xbf)[i] = o;
    }
    return;
  }
  int bb = b - nbConv;
  if (bb < nbRp) {
    int i = bb * 256 + tid;
    if (i <= n) {
      int lo = 0, hi = e;
      while (lo < hi) {
        int mid = (lo + hi) >> 1;
        if (rows[mid] < i) lo = mid + 1; else hi = mid;
      }
      row_ptr[i] = lo;
    }
    return;
  }
  bb -= nbRp;
  if (bb < 8) { pack_bfrag_block(W1, g1, v1, Bf1, bb, tid); return; }
  if (bb < 16) { pack_bfrag_block(Wd, g2, v2, Bf2, bb - 8, tid); return; }
  if (bb == 16) { if (tid < D) bn_bias_block(W1, g1, beta1, mean1, v1, bnb, tid); return; }
  if (bb == 17) { if (tid < D) bn_bias_block(Wd, g2, beta2, mean2, v2, shd, tid); return; }
  int i = (bb - 18) * 256 + tid;
  if (i < e) {
    uint c = (uint)cols[i];
    float a = adj[i];
    ew1[i] = make_uint2(c, __float_as_uint(a));
    float w2 = a / (relc[rel[i]] + 1.0f);
    ew2[i] = make_uint2(c, __float_as_uint(w2));
  } else if (i == e) {
    ew1[i] = make_uint2(0u, 0u);
    ew2[i] = make_uint2(0u, 0u);
  }
}

// ---------------------------------------------------------------------------
// SpMM phase (CSR pull): 4 rows per wave, 16 lanes per row. Edge metas for a
// 16-edge chunk loaded cooperatively (lane m -> edge base+m) and broadcast
// via group-local __shfl; gathers issue in batches of 8 per lane (8 dwordx4
// in flight). Masked slots clamp to last edge (weight 0 -> L1-hot re-read).
// No early returns (callers barrier after).
// ---------------------------------------------------------------------------
template <bool SELF>
__device__ __forceinline__ float spmm_rows(
    const uint4* __restrict__ S4, const int* __restrict__ row_ptr,
    const uint2* __restrict__ ew, const float* __restrict__ ck,
    int r, bool valid, int lane, float acc[8]) {
  const int m = lane & 15;
  const int g16 = lane & 48;  // base lane of my 16-lane row group
  const int e0 = row_ptr[r];
  int len = row_ptr[r + 1] - e0;
  if (!valid) len = 0;
  int mx = len;
  mx = max(mx, __shfl_xor(mx, 16));
  mx = max(mx, __shfl_xor(mx, 32));  // wave-uniform
  const int lastOff = len > 0 ? len - 1 : 0;

#pragma unroll
  for (int j = 0; j < 8; ++j) acc[j] = 0.f;
  float ws = 0.f;

  for (int base = 0; base < mx; base += 16) {
    const int mo = base + m;
    const uint2 mym = ew[e0 + (mo < len ? mo : lastOff)];
    const float myw = (mo < len) ? __uint_as_float(mym.y) : 0.f;
#pragma unroll
    for (int h = 0; h < 2; ++h) {
      if (base + h * 8 >= mx) break;  // wave-uniform
      uint4 gv[8];
      float wv[8];
#pragma unroll
      for (int u = 0; u < 8; ++u) {
        const int src = g16 + h * 8 + u;
        const uint cidx = (uint)__shfl((int)mym.x, src);
        wv[u] = __shfl(myw, src);
        gv[u] = S4[(size_t)cidx * 16 + m];
      }
#pragma unroll
      for (int u = 0; u < 8; ++u) {
        const float w = wv[u];
        ws += w;
        acc[0] = fmaf(w, bflo(gv[u].x), acc[0]);
        acc[1] = fmaf(w, bfhi(gv[u].x), acc[1]);
        acc[2] = fmaf(w, bflo(gv[u].y), acc[2]);
        acc[3] = fmaf(w, bfhi(gv[u].y), acc[3]);
        acc[4] = fmaf(w, bflo(gv[u].z), acc[4]);
        acc[5] = fmaf(w, bfhi(gv[u].z), acc[5]);
        acc[6] = fmaf(w, bflo(gv[u].w), acc[6]);
        acc[7] = fmaf(w, bfhi(gv[u].w), acc[7]);
      }
    }
  }

  if (SELF && valid) {
    uint4 us = S4[(size_t)r * 16 + m];
    float cp = ck[r] + 1.0f;
    acc[0] = fmaf(cp, bflo(us.x), acc[0]);
    acc[1] = fmaf(cp, bfhi(us.x), acc[1]);
    acc[2] = fmaf(cp, bflo(us.y), acc[2]);
    acc[3] = fmaf(cp, bfhi(us.y), acc[3]);
    acc[4] = fmaf(cp, bflo(us.z), acc[4]);
    acc[5] = fmaf(cp, bfhi(us.z), acc[5]);
    acc[6] = fmaf(cp, bflo(us.w), acc[6]);
    acc[7] = fmaf(cp, bfhi(us.w), acc[7]);
  }
  return ws;
}

__device__ __forceinline__ uint4 pack_acc(const float acc[8]) {
  uint4 o;
  o.x = (uint)f2bf(acc[0]) | ((uint)f2bf(acc[1]) << 16);
  o.y = (uint)f2bf(acc[2]) | ((uint)f2bf(acc[3]) << 16);
  o.z = (uint)f2bf(acc[4]) | ((uint)f2bf(acc[5]) << 16);
  o.w = (uint)f2bf(acc[6]) | ((uint)f2bf(acc[7]) << 16);
  return o;
}

// ---------------------------------------------------------------------------
// Fused K2: spmm1 (16 rows/block via LDS) + GEMM1 + tanh, LDS-staged
// coalesced y1 writes. LDS ~9 KB -> 8 blocks/CU (wave-limited).
// ---------------------------------------------------------------------------
__global__ __launch_bounds__(256) void spmm_gemm1_kernel(
    const ushort* __restrict__ src, const int* __restrict__ row_ptr,
    const uint2* __restrict__ ew, const ushort* __restrict__ Bf,
    const float* __restrict__ bnb, const float* __restrict__ b1,
    ushort* __restrict__ y1, int n) {
  __shared__ ushort aggT[16 * AGG_S];
  __shared__ ushort y1T[16 * AGG_S];
  __shared__ float rsL[16];

  const int tid = threadIdx.x;
  const int wave = tid >> 6, lane = tid & 63;
  const int g = lane >> 4, m = lane & 15;
  const int rloc = wave * 4 + g;
  const int idx = (int)blockIdx.x * 16 + rloc;
  const bool valid = idx < n;
  const int r = valid ? idx : n - 1;

  // ---- phase A: spmm into registers, stage bf16 tile in LDS ----
  float acc[8];
  float ws = spmm_rows<false>(reinterpret_cast<const uint4*>(src), row_ptr,
                              ew, nullptr, r, valid, lane, acc);
  *reinterpret_cast<uint4*>(&aggT[rloc * AGG_S + m * 8]) = pack_acc(acc);
  if (m == 0) rsL[rloc] = ws;
  __syncthreads();

  // ---- phase B: 16x128 @ 128x128 MFMA; wave handles nt = {2w, 2w+1} ----
  const bf16x8* Bv = reinterpret_cast<const bf16x8*>(Bf);
  bf16x8 af[4];
#pragma unroll
  for (int kc = 0; kc < 4; ++kc)
    af[kc] = *reinterpret_cast<const bf16x8*>(&aggT[m * AGG_S + kc * 32 + g * 8]);

  f32x4 acc2[2];
  acc2[0] = (f32x4){0.f, 0.f, 0.f, 0.f};
  acc2[1] = (f32x4){0.f, 0.f, 0.f, 0.f};
  const int nt0 = wave * 2;
#pragma unroll
  for (int kc = 0; kc < 4; ++kc) {
#pragma unroll
    for (int t = 0; t < 2; ++t) {
      bf16x8 b = Bv[(kc * 8 + nt0 + t) * 64 + lane];
      acc2[t] = __builtin_amdgcn_mfma_f32_16x16x32_bf16(b, af[kc], acc2[t], 0, 0, 0);
    }
  }

  const float rs = rsL[m];
#pragma unroll
  for (int t = 0; t < 2; ++t) {
    const int c = (nt0 + t) * 16 + g * 4;
    const float4 bn = *reinterpret_cast<const float4*>(&bnb[c]);
    const float4 bb = *reinterpret_cast<const float4*>(&b1[c]);
    ushort4 ov;
    ov.x = f2bf(tanhf(acc2[t][0] + rs * bn.x + bb.x));
    ov.y = f2bf(tanhf(acc2[t][1] + rs * bn.y + bb.y));
    ov.z = f2bf(tanhf(acc2[t][2] + rs * bn.z + bb.z));
    ov.w = f2bf(tanhf(acc2[t][3] + rs * bn.w + bb.w));
    *reinterpret_cast<ushort4*>(&y1T[m * AGG_S + c]) = ov;
  }
  __syncthreads();

  // ---- coalesced copy: 16 rows x 256 B = 4 KB, 1 uint4 per thread ----
  const int row = tid >> 4, col = tid & 15;
  uint4 v = *reinterpret_cast<const uint4*>(&y1T[row * AGG_S + col * 8]);
  const int gidx = (int)blockIdx.x * 16 + row;
  if (gidx < n) reinterpret_cast<uint4*>(y1)[(size_t)gidx * 16 + col] = v;
}

// ---------------------------------------------------------------------------
// Fused K3: spmm2(+self) + GEMM2 + bias + tri-L2-normalize + DIRECT stores.
// The out-LDS staging is gone: per (row, wave) each fragment group's stores
// form a 128-B line-aligned contiguous chunk already, so direct stores lose
// nothing -- and LDS drops 26 KB -> ~6 KB, lifting the occupancy cap from
// 6 to 8 blocks/CU (more gather misses in flight).
// ---------------------------------------------------------------------------
__global__ __launch_bounds__(256) void spmm_gemm2_kernel(
    const ushort* __restrict__ src /*y1bf*/, const int* __restrict__ row_ptr,
    const uint2* __restrict__ ew, const ushort* __restrict__ Bf,
    const float* __restrict__ shd, const float* __restrict__ bd,
    const float* __restrict__ ck, const float* __restrict__ x,
    float* __restrict__ out, int n) {
  __shared__ ushort aggT[16 * AGG_S];
  __shared__ float rsL[16];
  __shared__ float sp0[4][16], sp1[4][16], sp2[4][16];

  const int tid = threadIdx.x;
  const int wave = tid >> 6, lane = tid & 63;
  const int g = lane >> 4, m = lane & 15;
  const int rloc = wave * 4 + g;
  const int idx = (int)blockIdx.x * 16 + rloc;
  const bool valid = idx < n;
  const int r = valid ? idx : n - 1;

  // ---- phase A: spmm with self term ----
  float acc[8];
  float ws = spmm_rows<true>(reinterpret_cast<const uint4*>(src), row_ptr,
                             ew, ck, r, valid, lane, acc);
  *reinterpret_cast<uint4*>(&aggT[rloc * AGG_S + m * 8]) = pack_acc(acc);
  if (m == 0) rsL[rloc] = ws;
  __syncthreads();

  // ---- phase B: GEMM; lane (g,m) owns row m, cols {nt0,nt0+1}*16+g*4 ----
  const bf16x8* Bv = reinterpret_cast<const bf16x8*>(Bf);
  bf16x8 af[4];
#pragma unroll
  for (int kc = 0; kc < 4; ++kc)
    af[kc] = *reinterpret_cast<const bf16x8*>(&aggT[m * AGG_S + kc * 32 + g * 8]);

  f32x4 acc2[2];
  acc2[0] = (f32x4){0.f, 0.f, 0.f, 0.f};
  acc2[1] = (f32x4){0.f, 0.f, 0.f, 0.f};
  const int nt0 = wave * 2;
#pragma unroll
  for (int kc = 0; kc < 4; ++kc) {
#pragma unroll
    for (int t = 0; t < 2; ++t) {
      bf16x8 b = Bv[(kc * 8 + nt0 + t) * 64 + lane];
      acc2[t] = __builtin_amdgcn_mfma_f32_16x16x32_bf16(b, af[kc], acc2[t], 0, 0, 0);
    }
  }

  // x / y1 col-slices: wave w covers cols w*32..w*32+31 of every tile row.
  const int rrow = (int)blockIdx.x * 16 + m;   // finalize row of this lane
  const int rm = rrow < n ? rrow : n - 1;
  const int c0 = wave * 32 + g * 8;
  const float4 xv0 = *reinterpret_cast<const float4*>(&x[(size_t)rm * D + c0]);
  const float4 xv1 = *reinterpret_cast<const float4*>(&x[(size_t)rm * D + c0 + 4]);
  const uint4 yv = *reinterpret_cast<const uint4*>(&src[(size_t)rm * D + c0]);
  const float ya = bflo(yv.x), yb = bfhi(yv.x), yc = bflo(yv.y), yd = bfhi(yv.y);
  const float ye = bflo(yv.z), yf = bfhi(yv.z), yg = bflo(yv.w), yh = bfhi(yv.w);

  float s0p = xv0.x * xv0.x + xv0.y * xv0.y + xv0.z * xv0.z + xv0.w * xv0.w +
              xv1.x * xv1.x + xv1.y * xv1.y + xv1.z * xv1.z + xv1.w * xv1.w;
  float s1p = ya * ya + yb * yb + yc * yc + yd * yd +
              ye * ye + yf * yf + yg * yg + yh * yh;

  const float rbias = rsL[m] + ck[rm] + 1.0f;
  float s2p = 0.f;
#pragma unroll
  for (int t = 0; t < 2; ++t) {
    const int c = (nt0 + t) * 16 + g * 4;
    const float4 sh = *reinterpret_cast<const float4*>(&shd[c]);
    const float4 bb = *reinterpret_cast<const float4*>(&bd[c]);
    acc2[t][0] += rbias * sh.x + bb.x;
    acc2[t][1] += rbias * sh.y + bb.y;
    acc2[t][2] += rbias * sh.z + bb.z;
    acc2[t][3] += rbias * sh.w + bb.w;
    s2p += acc2[t][0] * acc2[t][0] + acc2[t][1] * acc2[t][1] +
           acc2[t][2] * acc2[t][2] + acc2[t][3] * acc2[t][3];
  }

  // reduce over the 4 g-groups (same finalize row m) within the wave
  s0p += __shfl_xor(s0p, 16); s0p += __shfl_xor(s0p, 32);
  s1p += __shfl_xor(s1p, 16); s1p += __shfl_xor(s1p, 32);
  s2p += __shfl_xor(s2p, 16); s2p += __shfl_xor(s2p, 32);
  if (lane < 16) { sp0[wave][lane] = s0p; sp1[wave][lane] = s1p; sp2[wave][lane] = s2p; }
  __syncthreads();

  const float s0 = sp0[0][m] + sp0[1][m] + sp0[2][m] + sp0[3][m];
  const float s1 = sp1[0][m] + sp1[1][m] + sp1[2][m] + sp1[3][m];
  const float s2 = sp2[0][m] + sp2[1][m] + sp2[2][m] + sp2[3][m];
  const float i0 = 1.0f / sqrtf(fmaxf(s0, L2_EPS));
  const float i1 = 1.0f / sqrtf(fmaxf(s1, L2_EPS));
  const float i2 = 1.0f / sqrtf(fmaxf(s2, L2_EPS));
  const float tot = s0 * i0 * i0 + s1 * i1 * i1 + s2 * i2 * i2;
  const float sc = 1.0f / sqrtf(fmaxf(tot, L2_EPS));
  const float f0 = i0 * sc, f1 = i1 * sc, f2 = i2 * sc;

  // ---- direct stores: every (row, wave) group writes 128-B aligned runs ----
  if (rrow < n) {
    float* orow = out + (size_t)rrow * 384;
    *reinterpret_cast<float4*>(&orow[c0]) =
        make_float4(xv0.x * f0, xv0.y * f0, xv0.z * f0, xv0.w * f0);
    *reinterpret_cast<float4*>(&orow[c0 + 4]) =
        make_float4(xv1.x * f0, xv1.y * f0, xv1.z * f0, xv1.w * f0);
    *reinterpret_cast<float4*>(&orow[128 + c0]) =
        make_float4(ya * f1, yb * f1, yc * f1, yd * f1);
    *reinterpret_cast<float4*>(&orow[128 + c0 + 4]) =
        make_float4(ye * f1, yf * f1, yg * f1, yh * f1);
#pragma unroll
    for (int t = 0; t < 2; ++t) {
      const int c = (nt0 + t) * 16 + g * 4;
      *reinterpret_cast<float4*>(&orow[256 + c]) =
          make_float4(acc2[t][0] * f2, acc2[t][1] * f2,
                      acc2[t][2] * f2, acc2[t][3] * f2);
    }
  }
}

// ---------------------------------------------------------------------------
extern "C" void kernel_launch(void* const* d_in, const int* in_sizes, int n_in,
                              void* d_out, int out_size, void* d_ws, size_t ws_size,
                              hipStream_t stream) {
  const float* x      = (const float*)d_in[0];
  const int*   rows   = (const int*)d_in[1];
  const int*   cols   = (const int*)d_in[2];
  const float* adj    = (const float*)d_in[3];
  const int*   rel    = (const int*)d_in[4];
  const float* gamma1 = (const float*)d_in[5];
  const float* beta1  = (const float*)d_in[6];
  const float* mean1  = (const float*)d_in[7];
  const float* var1   = (const float*)d_in[8];
  const float* W1     = (const float*)d_in[9];
  const float* b1     = (const float*)d_in[10];
  const float* gamma2 = (const float*)d_in[11];
  const float* beta2  = (const float*)d_in[12];
  const float* mean2  = (const float*)d_in[13];
  const float* var2   = (const float*)d_in[14];
  const float* relc   = (const float*)d_in[15];
  const float* ck     = (const float*)d_in[16];
  const float* Wd     = (const float*)d_in[17];
  const float* bd     = (const float*)d_in[18];
  float* out = (float*)d_out;

  const int n = in_sizes[0] / D;
  const int e = in_sizes[1];
  size_t nd = (size_t)n * D;

  char* p = (char*)d_ws;
  ushort* xbf   = (ushort*)p; p += nd * 2;
  ushort* y1bf  = (ushort*)p; p += nd * 2;
  ushort* Bf1   = (ushort*)p; p += 32768;
  ushort* Bf2   = (ushort*)p; p += 32768;
  float*  bnb   = (float*)p;  p += 512;
  float*  shd   = (float*)p;  p += 512;
  p = (char*)(((uintptr_t)p + 15) & ~(uintptr_t)15);
  uint2* ew1    = (uint2*)p;  p += (size_t)(e + 1) * 8;
  uint2* ew2    = (uint2*)p;  p += (size_t)(e + 1) * 8;
  int* row_ptr  = (int*)p;    p += (size_t)(n + 1) * 4;

  const int n4 = (int)(nd / 4);
  const int nbConv = (n4 + 255) / 256;
  const int nbRp = (n + 1 + 255) / 256;
  const int nbEw = (e + 1 + 255) / 256;
  const int nbPrep = nbConv + nbRp + 18 + nbEw;

  prep_kernel<<<nbPrep, 256, 0, stream>>>(
      x, xbf, n4, rows, row_ptr, n, e,
      W1, gamma1, var1, Bf1, Wd, gamma2, var2, Bf2,
      beta1, mean1, bnb, beta2, mean2, shd,
      cols, adj, rel, relc, ew1, ew2, nbConv, nbRp);

  const int fblocks = (n + 15) / 16;
  spmm_gemm1_kernel<<<fblocks, 256, 0, stream>>>(
      xbf, row_ptr, ew1, Bf1, bnb, b1, y1bf, n);
  spmm_gemm2_kernel<<<fblocks, 256, 0, stream>>>(
      y1bf, row_ptr, ew2, Bf2, shd, bd, ck, x, out, n);
}